// Round 7
// baseline (2377.748 us; speedup 1.0000x reference)
//
#include <hip/hip_runtime.h>
#include <math.h>

// WFR Sinkhorn, B=8, I=J=1024, NITER=50, eps=0.1 — persistent cooperative kernel.
//
// Design (round 7): 256 blocks x 512 threads; block = (batch beta=bid&7, 32 rows)
// as 2 panels x 16 rows (panel = 4 waves). Thread owns 16 rows x 4 cols of K in
// registers (16 x float4 = 64 VGPR) for the entire run — K never exists in
// memory (rebuilt from C only on absorb; final forced absorb streams C and
// writes K to d_out). 512-thread blocks keep the VGPR cap at 256 (no spill
// cliff); grid 256 fills all CUs. batch = bid&7 puts a batch's 32 blocks on one
// XCD (round-robin heuristic, perf-only). Col partials combined across the 2
// panels in LDS -> ONE global atomicAdd per (block,col) = 262144 atomics/iter.
//
// Cross-block protocol:
// - s2 col sums: 3-slot rotation; epoch t zeroes slot (t+1)%3 (own batch cols;
//   its readers finished before barrier t-1), accumulates t%3, reads (t+2)%3.
// - per-batch barrier: monotone counter (32 arrivals), release-arrive/acquire-spin.
// - all cross-block data via agent-scope atomics (per-XCD L2s not coherent).
// - absorb machinery (dead at runtime here: ratios O(1e4) vs the 1e22 threshold;
//   forced absorb at ii=49 handled in the epilogue):
//   * own-batch b-side: every block of a batch spans all 1024 cols and holds
//     identical v/ev state, so the threshold test is block-uniform per batch ->
//     exact same-iteration absorb, deterministic (no flag traffic needed).
//   * own-batch a-side: ha[slot][beta] written during t's row pass, consumed by
//     own batch at t+1 (== reference's end-of-t absorb), barrier-ordered.
//   * cross-batch: chunk-0 block samples ha|hb of all batches during t and
//     publishes ONE value to xflag[beta][t%3]; all blocks of beta consume
//     xflag[beta][(t+2)%3] at t+1 -> batch-consistent by construction (the
//     sampled value is best-effort under batch drift; exact cross-batch
//     semantics would need a global barrier per iteration).

#define EPSV     0.1f
#define HUGEV    1e30f
#define RTHR     1e22f       // BIG^(1+eps): clip(pow(r,1/(1+eps))) > BIG  <=>  r > RTHR
#define SMALLV   1e-7f
#define P_COEF   0.90909090909090912f   // 1/(1+eps)
#define DXV      (1.0f/1024.0f)
#define DYV      (1.0f/1024.0f)

constexpr int NITER = 50;

__device__ __forceinline__ float powp(float x) {
    // x > 0 at all call sites; pow(x,p) = exp(p*log(x)) (matches XLA lowering).
    return expf(P_COEF * logf(x));
}

__device__ __forceinline__ float aload(const float* p) {
    return __hip_atomic_load((float*)p, __ATOMIC_RELAXED, __HIP_MEMORY_SCOPE_AGENT);
}
__device__ __forceinline__ unsigned aloadu(const unsigned* p) {
    return __hip_atomic_load((unsigned*)p, __ATOMIC_RELAXED, __HIP_MEMORY_SCOPE_AGENT);
}
__device__ __forceinline__ void astore(float* p, float v) {
    __hip_atomic_store(p, v, __ATOMIC_RELAXED, __HIP_MEMORY_SCOPE_AGENT);
}
__device__ __forceinline__ void astoreu(unsigned* p, unsigned v) {
    __hip_atomic_store(p, v, __ATOMIC_RELAXED, __HIP_MEMORY_SCOPE_AGENT);
}

// Per-batch barrier: monotone counter, 32 blocks/batch. Release on arrive makes
// this block's prior vmem (col atomics, zero/flag stores) visible before the
// count; acquire on the spin load orders subsequent reads.
__device__ __forceinline__ void batch_barrier(unsigned* ctr, unsigned target, int tid) {
    __threadfence();
    __syncthreads();
    if (tid == 0) {
        __hip_atomic_fetch_add(ctr, 1u, __ATOMIC_RELEASE, __HIP_MEMORY_SCOPE_AGENT);
        while (__hip_atomic_load(ctr, __ATOMIC_ACQUIRE, __HIP_MEMORY_SCOPE_AGENT) < target)
            __builtin_amdgcn_s_sleep(2);
    }
    __syncthreads();
}

// Butterfly fold of 8 row-partials across a wave; lanes specialize by bitrev3;
// lanes 0..7 write wave totals to red[w*16 + roff + row].
__device__ __forceinline__ void fold_rows8(float (&p)[8], int lane, float* red,
                                           int w, int roff) {
    #pragma unroll
    for (int step = 0; step < 3; ++step) {
        const int m = 1 << step;
        const int half = 4 >> step;          // 4,2,1
        const bool hi = (lane & m) != 0;
        #pragma unroll
        for (int i = 0; i < half; ++i) {
            float keep = hi ? p[i + half] : p[i];
            float send = hi ? p[i] : p[i + half];
            p[i] = keep + __shfl_xor(send, m);
        }
    }
    float r = p[0];
    r += __shfl_xor(r, 8);
    r += __shfl_xor(r, 16);
    r += __shfl_xor(r, 32);
    int row = ((lane & 1) << 2) | (lane & 2) | ((lane & 4) >> 2);
    if (lane < 8) red[w * 16 + roff + row] = r;
}

// ---------------------------------------------------------------------------
// init: ws is poisoned 0xAA before every timed launch. grid 32 x 256.
// ---------------------------------------------------------------------------
__global__ void initws(float* __restrict__ s2, float* __restrict__ rnu,
                       float* __restrict__ accT, float* __restrict__ accC1,
                       unsigned* __restrict__ bctr, unsigned* __restrict__ flg) {
    int i = blockIdx.x * 256 + threadIdx.x;   // 0..8191
    s2[i] = 0.f; s2[8192 + i] = 0.f; s2[16384 + i] = 0.f;
    rnu[i] = 0.f;
    if (i < 8)  { accT[i] = 0.f; accC1[i] = 0.f; bctr[i] = 0u; }
    if (i < 72) flg[i] = 0u;   // ha[3][8] + hb[3][8] + xflag[8][3]
}

// ---------------------------------------------------------------------------
// persistent kernel: grid 256 (8 batches x 32 chunks), 512 threads, 1 block/CU.
// ---------------------------------------------------------------------------
__global__ __launch_bounds__(512, 2) void sinkhorn_persist(
    const float* __restrict__ C, const float* __restrict__ mu,
    const float* __restrict__ nu, float* __restrict__ out,
    float* __restrict__ s2, float* __restrict__ rnu,
    unsigned* __restrict__ bctr, unsigned* __restrict__ flg,
    float* __restrict__ accT, float* __restrict__ accC1)
{
    const int tid   = threadIdx.x;        // 0..511
    const int bid   = blockIdx.x;         // 0..255
    const int beta  = bid & 7;
    const int chunk = bid >> 3;           // 0..31
    const int r0    = chunk << 5;         // 32 rows per block
    const int lane  = tid & 63;
    const int w     = tid >> 6;           // wave 0..7
    const int p     = tid >> 8;           // panel 0..1 (16 rows each)
    const int tp    = tid & 255;          // thread-in-panel
    const int col0  = tp << 2;
    const int kbase = (beta * 1024 + r0 + p * 16) * 1024 + col0;

    unsigned* ha    = flg;                // [3][8] a-side absorb signals
    unsigned* hb    = flg + 24;           // [3][8] b-side cross signals
    unsigned* xflag = flg + 48;           // [8][3] per-batch cross mailbox

    __shared__ float a_s[32], u_s[32], eu_s[32];
    __shared__ float red_s[128];          // [wave 0..7][row 0..15]
    __shared__ float s2p_s[2][1024];      // per-panel col partials (8 KB)
    __shared__ float tr_s[8];

    const float4 nuv = *reinterpret_cast<const float4*>(nu + col0);
    float4 vv = make_float4(0.f, 0.f, 0.f, 0.f);
    float4 ev = make_float4(1.f, 1.f, 1.f, 1.f);
    const float muv = (tid < 32) ? mu[r0 + tid] : 0.f;
    if (tid < 32) { u_s[tid] = 0.f; eu_s[tid] = 1.f; }

    // t=0: K = clip(exp(-C/eps)) into registers (C streamed from HBM once)
    float4 kr[16];
    #pragma unroll
    for (int i = 0; i < 16; ++i) {
        float4 cv = *reinterpret_cast<const float4*>(C + kbase + i * 1024);
        kr[i].x = fminf(expf(-cv.x * 10.0f), HUGEV);
        kr[i].y = fminf(expf(-cv.y * 10.0f), HUGEV);
        kr[i].z = fminf(expf(-cv.z * 10.0f), HUGEV);
        kr[i].w = fminf(expf(-cv.w * 10.0f), HUGEV);
    }
    float4 bu = make_float4(1.f, 1.f, 1.f, 1.f);
    __syncthreads();

    for (int t = 0; t < NITER; ++t) {
        const int slot_cur  = t % 3;
        const int slot_next = (t + 1) % 3;
        const int slot_prev = (t + 2) % 3;

        if (t > 0) {
            // ---- b(t-1) from s2(t-1); absorb decision for step t-1 ----------
            const float* sp = s2 + slot_prev * 8192 + beta * 1024 + col0;
            float s0 = aload(sp + 0), s1 = aload(sp + 1);
            float s2e = aload(sp + 2), s3 = aload(sp + 3);
            // carry: own a-side(t-1) + cross mailbox (deterministic per batch)
            int carry = 0;
            if (tid == 0)
                carry = (aloadu(ha + slot_prev * 8 + beta) |
                         aloadu(xflag + beta * 3 + slot_prev)) ? 1 : 0;
            // cross-batch collector: sample all batches' signals, publish for t+1
            if (chunk == 0 && tid == 64) {
                unsigned f = 0;
                #pragma unroll
                for (int b = 0; b < 8; ++b)
                    f |= aloadu(ha + slot_prev * 8 + b) | aloadu(hb + slot_prev * 8 + b);
                astoreu(xflag + beta * 3 + slot_cur, f);
            }
            float b0 = fminf(powp(nuv.x / (ev.x * s0)),  HUGEV);
            float b1 = fminf(powp(nuv.y / (ev.y * s1)),  HUGEV);
            float b2 = fminf(powp(nuv.z / (ev.z * s2e)), HUGEV);
            float b3 = fminf(powp(nuv.w / (ev.w * s3)),  HUGEV);
            // b(t-1) > BIG  <=>  s2*ev*RTHR < nu  (mul form, no div/pow)
            bool hotb = (s0 * ev.x * RTHR < nuv.x) || (s1 * ev.y * RTHR < nuv.y) ||
                        (s2e * ev.z * RTHR < nuv.z) || (s3 * ev.w * RTHR < nuv.w);
            if (__any((int)hotb) && lane == 0)
                atomicOr(hb + slot_cur * 8 + beta, 1u);   // cross signal only
            int flag = __syncthreads_or((int)hotb | carry);
            if (flag) {
                // absorb(t-1): u += eps log a, v += eps log b, K rebuilt, b = 1
                float vn0 = EPSV * logf(b0) + vv.x;
                float vn1 = EPSV * logf(b1) + vv.y;
                float vn2 = EPSV * logf(b2) + vv.z;
                float vn3 = EPSV * logf(b3) + vv.w;
                if (tid < 32) {
                    float un = EPSV * logf(a_s[tid]) + u_s[tid];
                    u_s[tid] = un;  eu_s[tid] = expf(un);
                }
                vv = make_float4(vn0, vn1, vn2, vn3);
                ev = make_float4(expf(vn0), expf(vn1), expf(vn2), expf(vn3));
                bu = make_float4(1.f, 1.f, 1.f, 1.f);
                __syncthreads();
                #pragma unroll
                for (int i = 0; i < 16; ++i) {
                    float4 cv = *reinterpret_cast<const float4*>(C + kbase + i * 1024);
                    float un = u_s[p * 16 + i];
                    kr[i].x = fminf(expf((un + vn0 - cv.x) * 10.0f), HUGEV);
                    kr[i].y = fminf(expf((un + vn1 - cv.y) * 10.0f), HUGEV);
                    kr[i].z = fminf(expf((un + vn2 - cv.z) * 10.0f), HUGEV);
                    kr[i].w = fminf(expf((un + vn3 - cv.w) * 10.0f), HUGEV);
                }
            } else {
                bu = make_float4(b0, b1, b2, b3);
            }
        }

        // ---- row pass: s_i = sum_j K_ij b_j dy ; a_i ------------------------
        float part[8];
        #pragma unroll
        for (int i = 0; i < 8; ++i)
            part[i] = kr[i].x * bu.x + kr[i].y * bu.y + kr[i].z * bu.z + kr[i].w * bu.w;
        fold_rows8(part, lane, red_s, w, 0);
        #pragma unroll
        for (int i = 0; i < 8; ++i)
            part[i] = kr[i + 8].x * bu.x + kr[i + 8].y * bu.y + kr[i + 8].z * bu.z + kr[i + 8].w * bu.w;
        fold_rows8(part, lane, red_s, w, 8);
        __syncthreads();
        if (tid < 32) {
            const float* rb = red_s + (tid >> 4) * 64 + (tid & 15);
            float s  = (rb[0] + rb[16] + rb[32] + rb[48]) * DYV;
            float rr = muv / (eu_s[tid] * s);
            float av = fminf(powp(rr), HUGEV);
            a_s[tid] = av;
            if (__any((int)(rr > RTHR)) && tid == 0)
                atomicOr(ha + slot_cur * 8 + beta, 1u);
        }
        __syncthreads();

        // ---- col pass: panel partials -> LDS combine -> 1 atomic per col ----
        float c0 = 0.f, c1 = 0.f, c2 = 0.f, c3 = 0.f;
        #pragma unroll
        for (int i = 0; i < 16; ++i) {
            float ai = a_s[p * 16 + i];
            c0 += kr[i].x * ai; c1 += kr[i].y * ai;
            c2 += kr[i].z * ai; c3 += kr[i].w * ai;
        }
        *reinterpret_cast<float4*>(&s2p_s[p][col0]) = make_float4(c0, c1, c2, c3);
        __syncthreads();
        if (tid < 256) {
            int cc = tid << 2;
            float4 q0 = *reinterpret_cast<const float4*>(&s2p_s[0][cc]);
            float4 q1 = *reinterpret_cast<const float4*>(&s2p_s[1][cc]);
            float* d = s2 + slot_cur * 8192 + beta * 1024 + cc;
            atomicAdd(d + 0, (q0.x + q1.x) * DXV);
            atomicAdd(d + 1, (q0.y + q1.y) * DXV);
            atomicAdd(d + 2, (q0.z + q1.z) * DXV);
            atomicAdd(d + 3, (q0.w + q1.w) * DXV);
        }
        // zero own batch's cols of slot_next (32 chunks x 32 = 1024; last read t-1)
        if (tid < 32)
            astore(s2 + slot_next * 8192 + beta * 1024 + chunk * 32 + tid, 0.0f);
        if (chunk == 0 && tid == 0) {
            astoreu(ha + slot_next * 8 + beta, 0u);
            astoreu(hb + slot_next * 8 + beta, 0u);
            astoreu(xflag + beta * 3 + slot_next, 0u);
        }
        batch_barrier(bctr + beta, 32u * (unsigned)(t + 1), tid);
    }

    // ---- final forced absorb (ii=49) + K output + reductions ---------------
    {
        const float* sp = s2 + ((NITER - 1) % 3) * 8192 + beta * 1024 + col0;
        float s0 = aload(sp + 0), s1 = aload(sp + 1);
        float s2e = aload(sp + 2), s3 = aload(sp + 3);
        float b0 = fminf(powp(nuv.x / (ev.x * s0)),  HUGEV);
        float b1 = fminf(powp(nuv.y / (ev.y * s1)),  HUGEV);
        float b2 = fminf(powp(nuv.z / (ev.z * s2e)), HUGEV);
        float b3 = fminf(powp(nuv.w / (ev.w * s3)),  HUGEV);
        float vn0 = EPSV * logf(b0) + vv.x;
        float vn1 = EPSV * logf(b1) + vv.y;
        float vn2 = EPSV * logf(b2) + vv.z;
        float vn3 = EPSV * logf(b3) + vv.w;
        if (tid < 32) u_s[tid] = EPSV * logf(a_s[tid]) + u_s[tid];
        __syncthreads();

        float* Kout = out + 24;
        float tacc = 0.f, cc0 = 0.f, cc1 = 0.f, cc2 = 0.f, cc3 = 0.f;
        float part[8];
        #pragma unroll
        for (int i = 0; i < 8; ++i) {
            int off = kbase + i * 1024;
            float4 cv = *reinterpret_cast<const float4*>(C + off);
            float un = u_s[p * 16 + i];
            float4 kv;
            kv.x = fminf(expf((un + vn0 - cv.x) * 10.0f), HUGEV);
            kv.y = fminf(expf((un + vn1 - cv.y) * 10.0f), HUGEV);
            kv.z = fminf(expf((un + vn2 - cv.z) * 10.0f), HUGEV);
            kv.w = fminf(expf((un + vn3 - cv.w) * 10.0f), HUGEV);
            *reinterpret_cast<float4*>(Kout + off) = kv;
            part[i] = kv.x + kv.y + kv.z + kv.w;
            tacc += kv.x * cv.x + kv.y * cv.y + kv.z * cv.z + kv.w * cv.w;
            cc0 += kv.x; cc1 += kv.y; cc2 += kv.z; cc3 += kv.w;
        }
        fold_rows8(part, lane, red_s, w, 0);
        #pragma unroll
        for (int i = 8; i < 16; ++i) {
            int off = kbase + i * 1024;
            float4 cv = *reinterpret_cast<const float4*>(C + off);
            float un = u_s[p * 16 + i];
            float4 kv;
            kv.x = fminf(expf((un + vn0 - cv.x) * 10.0f), HUGEV);
            kv.y = fminf(expf((un + vn1 - cv.y) * 10.0f), HUGEV);
            kv.z = fminf(expf((un + vn2 - cv.z) * 10.0f), HUGEV);
            kv.w = fminf(expf((un + vn3 - cv.w) * 10.0f), HUGEV);
            *reinterpret_cast<float4*>(Kout + off) = kv;
            part[i - 8] = kv.x + kv.y + kv.z + kv.w;
            tacc += kv.x * cv.x + kv.y * cv.y + kv.z * cv.z + kv.w * cv.w;
            cc0 += kv.x; cc1 += kv.y; cc2 += kv.z; cc3 += kv.w;
        }
        fold_rows8(part, lane, red_s, w, 8);

        *reinterpret_cast<float4*>(&s2p_s[p][col0]) = make_float4(cc0, cc1, cc2, cc3);

        float r = tacc;
        #pragma unroll
        for (int m = 32; m >= 1; m >>= 1) r += __shfl_xor(r, m);
        if (lane == 0) tr_s[w] = r;
        __syncthreads();

        if (tid < 256) {                    // rnu: panel combine -> atomic
            int cc = tid << 2;
            float4 q0 = *reinterpret_cast<const float4*>(&s2p_s[0][cc]);
            float4 q1 = *reinterpret_cast<const float4*>(&s2p_s[1][cc]);
            float* rn = rnu + beta * 1024 + cc;
            atomicAdd(rn + 0, (q0.x + q1.x) * DXV);
            atomicAdd(rn + 1, (q0.y + q1.y) * DXV);
            atomicAdd(rn + 2, (q0.z + q1.z) * DXV);
            atomicAdd(rn + 3, (q0.w + q1.w) * DXV);
        }
        if (tid < 32) {                     // cons1 partial for this block's rows
            const float* rb = red_s + (tid >> 4) * 64 + (tid & 15);
            float rmu = (rb[0] + rb[16] + rb[32] + rb[48]) * DYV;
            float dv = rmu / (muv + SMALLV);
            float kl = muv * (dv * logf(dv + SMALLV) - dv + 1.f);
            #pragma unroll
            for (int m = 32; m >= 1; m >>= 1) kl += __shfl_xor(kl, m);
            if (tid == 0) atomicAdd(accC1 + beta, kl * DXV);
        }
        if (tid == 0) {
            float tt = 0.f;
            #pragma unroll
            for (int i = 0; i < 8; ++i) tt += tr_s[i];
            atomicAdd(accT + beta, tt);
        }
        batch_barrier(bctr + beta, 32u * (unsigned)(NITER + 1), tid);

        if (chunk == 0) {
            // cons2 + scalar outputs for batch beta
            if (tid < 256) {
                const float* rn = rnu + beta * 1024 + (tid << 2);
                float q0 = aload(rn + 0), q1 = aload(rn + 1);
                float q2 = aload(rn + 2), q3 = aload(rn + 3);
                float acc = 0.f;
                { float dv = q0 / (nuv.x + SMALLV); acc += nuv.x * (dv * logf(dv + SMALLV) - dv + 1.f); }
                { float dv = q1 / (nuv.y + SMALLV); acc += nuv.y * (dv * logf(dv + SMALLV) - dv + 1.f); }
                { float dv = q2 / (nuv.z + SMALLV); acc += nuv.z * (dv * logf(dv + SMALLV) - dv + 1.f); }
                { float dv = q3 / (nuv.w + SMALLV); acc += nuv.w * (dv * logf(dv + SMALLV) - dv + 1.f); }
                #pragma unroll
                for (int m = 32; m >= 1; m >>= 1) acc += __shfl_xor(acc, m);
                if (lane == 0) tr_s[w] = acc;    // waves 0..3
            }
            __syncthreads();
            if (tid == 0) {
                out[16 + beta] = (tr_s[0] + tr_s[1] + tr_s[2] + tr_s[3]) * DYV;
                out[beta]      = __hip_atomic_load(accT + beta,  __ATOMIC_RELAXED,
                                                   __HIP_MEMORY_SCOPE_AGENT) * (DXV * DYV);
                out[8 + beta]  = __hip_atomic_load(accC1 + beta, __ATOMIC_RELAXED,
                                                   __HIP_MEMORY_SCOPE_AGENT);
            }
        }
    }
}

extern "C" void kernel_launch(void* const* d_in, const int* in_sizes, int n_in,
                              void* d_out, int out_size, void* d_ws, size_t ws_size,
                              hipStream_t stream) {
    const float* C  = (const float*)d_in[0];   // [8,1024,1024]
    const float* mu = (const float*)d_in[1];   // [1024]
    const float* nu = (const float*)d_in[2];   // [1024]
    float* out = (float*)d_out;                // transport[8] cons1[8] cons2[8] K[8M]

    // ws layout (floats); total ~129 KB
    float* w     = (float*)d_ws;
    float* s2    = w;                          // [3][8][1024] rotating col sums
    float* rnu   = w + 24576;                  // [8][1024]
    float* accT  = w + 32768;                  // [8]
    float* accC1 = w + 32776;                  // [8]
    unsigned* bctr = (unsigned*)(w + 32784);   // [8] per-batch barrier counters
    unsigned* flg  = (unsigned*)(w + 32792);   // [72] ha[3][8]+hb[3][8]+xflag[8][3]

    hipLaunchKernelGGL(initws, dim3(32), dim3(256), 0, stream,
                       s2, rnu, accT, accC1, bctr, flg);

    void* args[] = { (void*)&C, (void*)&mu, (void*)&nu, (void*)&out,
                     (void*)&s2, (void*)&rnu, (void*)&bctr, (void*)&flg,
                     (void*)&accT, (void*)&accC1 };
    hipError_t err = hipLaunchCooperativeKernel((const void*)sinkhorn_persist,
                                                dim3(256), dim3(512), args, 0, stream);
    if (err != hipSuccess) {
        // Fallback: plain launch. 256 blocks = 1/CU on an otherwise-idle device,
        // so all blocks are co-resident and the spin barriers remain safe.
        hipLaunchKernelGGL(sinkhorn_persist, dim3(256), dim3(512), 0, stream,
                           C, mu, nu, out, s2, rnu, bctr, flg, accT, accC1);
    }
}

// Round 10
// 681.724 us; speedup vs baseline: 3.4878x; 3.4878x over previous
//
#include <hip/hip_runtime.h>
#include <math.h>

// WFR Sinkhorn, B=8, I=J=1024, NITER=50, eps=0.1 — persistent cooperative kernel.
//
// Round 10 = round 8/9 barrier fix (never benched: acquisition timeouts), plus
// per-batch counter padding (64B stride) so the 8 barrier counters don't share
// one cache line at the coherence point.
//
// Post-mortem-driven fix of the r7 barrier (the only measured round):
//   r7: 2378 µs, VALUBusy 7%, WRITE_SIZE 265 MB (vs ~90 MB true traffic).
//   Cause: __threadfence() + ACQUIRE-spin/RELEASE-arrive lower to
//   buffer_wbl2/buffer_inv (whole-L2 writeback/invalidate) per poll/arrival on
//   gfx95x -> cache-maintenance storm (~47 µs/iter, +175 MB spurious HBM writes).
//   Fix: ALL cross-block data here uses agent-scope ops; SCOPE (not ordering)
//   drives the cache-bypass routing past the non-coherent per-XCD L2s to the
//   die-level coherence point, so RELAXED ops still observe remote writes.
//   Ordering = completion: __syncthreads() compiles to s_waitcnt vmcnt(0) +
//   s_barrier, so every thread's s2 atomics/zero-stores are complete before the
//   arrive. Fully RELAXED arrive + RELAXED spin -> zero cache maintenance.
//
// Design (unchanged from r7): 256 blocks x 512 threads; block = (batch beta=bid&7,
// 32 rows) as 2 panels x 16 rows. Thread owns 16 rows x 4 cols of K in registers
// (16 x float4) for the whole run — K never exists in memory (rebuilt from C only
// on absorb; final forced absorb streams C and writes K to d_out). Col partials
// combined across panels in LDS -> ONE global atomicAdd per (block,col).
// s2: 3-slot rotation (zero (t+1)%3, accumulate t%3, read (t+2)%3), per-batch
// monotone-counter barrier (32 arrivals). Absorb machinery dead at runtime for
// this input (ratios O(1e4) vs 1e22 threshold); forced absorb at ii=49 in epilogue.

#define EPSV     0.1f
#define HUGEV    1e30f
#define RTHR     1e22f       // BIG^(1+eps): clip(pow(r,1/(1+eps))) > BIG  <=>  r > RTHR
#define SMALLV   1e-7f
#define P_COEF   0.90909090909090912f   // 1/(1+eps)
#define DXV      (1.0f/1024.0f)
#define DYV      (1.0f/1024.0f)

constexpr int NITER = 50;
constexpr int CTR_STRIDE = 16;   // 16 u32 = 64 B: one cache line per batch counter

__device__ __forceinline__ float powp(float x) {
    // x > 0 at all call sites; pow(x,p) = exp(p*log(x)) (matches XLA lowering).
    return expf(P_COEF * logf(x));
}

__device__ __forceinline__ float aload(const float* p) {
    return __hip_atomic_load((float*)p, __ATOMIC_RELAXED, __HIP_MEMORY_SCOPE_AGENT);
}
__device__ __forceinline__ unsigned aloadu(const unsigned* p) {
    return __hip_atomic_load((unsigned*)p, __ATOMIC_RELAXED, __HIP_MEMORY_SCOPE_AGENT);
}
__device__ __forceinline__ void astore(float* p, float v) {
    __hip_atomic_store(p, v, __ATOMIC_RELAXED, __HIP_MEMORY_SCOPE_AGENT);
}
__device__ __forceinline__ void astoreu(unsigned* p, unsigned v) {
    __hip_atomic_store(p, v, __ATOMIC_RELAXED, __HIP_MEMORY_SCOPE_AGENT);
}

// Per-batch barrier: monotone counter (own 64B line), 32 blocks/batch. FULLY
// RELAXED by design: agent-scope ops complete at the die-level coherence point;
// __syncthreads() drains vmcnt(0) per thread, so all prior s2 atomics /
// zero-stores are globally visible before the arrive. No fences -> no
// buffer_wbl2/buffer_inv storms (the r7 bug: 2378 µs, 265 MB spurious writes).
__device__ __forceinline__ void batch_barrier(unsigned* ctr, unsigned target, int tid) {
    __syncthreads();
    if (tid == 0) {
        asm volatile("s_waitcnt vmcnt(0)" ::: "memory");   // belt-and-braces
        __hip_atomic_fetch_add(ctr, 1u, __ATOMIC_RELAXED, __HIP_MEMORY_SCOPE_AGENT);
        while (__hip_atomic_load(ctr, __ATOMIC_RELAXED, __HIP_MEMORY_SCOPE_AGENT) < target)
            __builtin_amdgcn_s_sleep(2);
    }
    __syncthreads();
}

// Butterfly fold of 8 row-partials across a wave; lanes specialize by bitrev3;
// lanes 0..7 write wave totals to red[w*16 + roff + row].
__device__ __forceinline__ void fold_rows8(float (&p)[8], int lane, float* red,
                                           int w, int roff) {
    #pragma unroll
    for (int step = 0; step < 3; ++step) {
        const int m = 1 << step;
        const int half = 4 >> step;          // 4,2,1
        const bool hi = (lane & m) != 0;
        #pragma unroll
        for (int i = 0; i < half; ++i) {
            float keep = hi ? p[i + half] : p[i];
            float send = hi ? p[i] : p[i + half];
            p[i] = keep + __shfl_xor(send, m);
        }
    }
    float r = p[0];
    r += __shfl_xor(r, 8);
    r += __shfl_xor(r, 16);
    r += __shfl_xor(r, 32);
    int row = ((lane & 1) << 2) | (lane & 2) | ((lane & 4) >> 2);
    if (lane < 8) red[w * 16 + roff + row] = r;
}

// ---------------------------------------------------------------------------
// init: ws is poisoned 0xAA before every timed launch. grid 32 x 256.
// ---------------------------------------------------------------------------
__global__ void initws(float* __restrict__ s2, float* __restrict__ rnu,
                       float* __restrict__ accT, float* __restrict__ accC1,
                       unsigned* __restrict__ bctr, unsigned* __restrict__ flg) {
    int i = blockIdx.x * 256 + threadIdx.x;   // 0..8191
    s2[i] = 0.f; s2[8192 + i] = 0.f; s2[16384 + i] = 0.f;
    rnu[i] = 0.f;
    if (i < 8)   { accT[i] = 0.f; accC1[i] = 0.f; }
    if (i < 128) bctr[i] = 0u;  // 8 counters x 16-u32 stride
    if (i < 72)  flg[i] = 0u;   // ha[3][8] + hb[3][8] + xflag[8][3]
}

// ---------------------------------------------------------------------------
// persistent kernel: grid 256 (8 batches x 32 chunks), 512 threads, 1 block/CU.
// ---------------------------------------------------------------------------
__global__ __launch_bounds__(512, 2) void sinkhorn_persist(
    const float* __restrict__ C, const float* __restrict__ mu,
    const float* __restrict__ nu, float* __restrict__ out,
    float* __restrict__ s2, float* __restrict__ rnu,
    unsigned* __restrict__ bctr, unsigned* __restrict__ flg,
    float* __restrict__ accT, float* __restrict__ accC1)
{
    const int tid   = threadIdx.x;        // 0..511
    const int bid   = blockIdx.x;         // 0..255
    const int beta  = bid & 7;
    const int chunk = bid >> 3;           // 0..31
    const int r0    = chunk << 5;         // 32 rows per block
    const int lane  = tid & 63;
    const int w     = tid >> 6;           // wave 0..7
    const int p     = tid >> 8;           // panel 0..1 (16 rows each)
    const int tp    = tid & 255;          // thread-in-panel
    const int col0  = tp << 2;
    const int kbase = (beta * 1024 + r0 + p * 16) * 1024 + col0;

    unsigned* ha    = flg;                // [3][8] a-side absorb signals
    unsigned* hb    = flg + 24;           // [3][8] b-side cross signals
    unsigned* xflag = flg + 48;           // [8][3] per-batch cross mailbox
    unsigned* myctr = bctr + beta * CTR_STRIDE;

    __shared__ float a_s[32], u_s[32], eu_s[32];
    __shared__ float red_s[128];          // [wave 0..7][row 0..15]
    __shared__ float s2p_s[2][1024];      // per-panel col partials (8 KB)
    __shared__ float tr_s[8];

    const float4 nuv = *reinterpret_cast<const float4*>(nu + col0);
    float4 vv = make_float4(0.f, 0.f, 0.f, 0.f);
    float4 ev = make_float4(1.f, 1.f, 1.f, 1.f);
    const float muv = (tid < 32) ? mu[r0 + tid] : 0.f;
    if (tid < 32) { u_s[tid] = 0.f; eu_s[tid] = 1.f; }

    // t=0: K = clip(exp(-C/eps)) into registers (C streamed from HBM once)
    float4 kr[16];
    #pragma unroll
    for (int i = 0; i < 16; ++i) {
        float4 cv = *reinterpret_cast<const float4*>(C + kbase + i * 1024);
        kr[i].x = fminf(expf(-cv.x * 10.0f), HUGEV);
        kr[i].y = fminf(expf(-cv.y * 10.0f), HUGEV);
        kr[i].z = fminf(expf(-cv.z * 10.0f), HUGEV);
        kr[i].w = fminf(expf(-cv.w * 10.0f), HUGEV);
    }
    float4 bu = make_float4(1.f, 1.f, 1.f, 1.f);
    __syncthreads();

    for (int t = 0; t < NITER; ++t) {
        const int slot_cur  = t % 3;
        const int slot_next = (t + 1) % 3;
        const int slot_prev = (t + 2) % 3;

        if (t > 0) {
            // ---- b(t-1) from s2(t-1); absorb decision for step t-1 ----------
            const float* sp = s2 + slot_prev * 8192 + beta * 1024 + col0;
            float s0 = aload(sp + 0), s1 = aload(sp + 1);
            float s2e = aload(sp + 2), s3 = aload(sp + 3);
            // carry: own a-side(t-1) + cross mailbox (deterministic per batch)
            int carry = 0;
            if (tid == 0)
                carry = (aloadu(ha + slot_prev * 8 + beta) |
                         aloadu(xflag + beta * 3 + slot_prev)) ? 1 : 0;
            // cross-batch collector: sample all batches' signals, publish for t+1
            if (chunk == 0 && tid == 64) {
                unsigned f = 0;
                #pragma unroll
                for (int b = 0; b < 8; ++b)
                    f |= aloadu(ha + slot_prev * 8 + b) | aloadu(hb + slot_prev * 8 + b);
                astoreu(xflag + beta * 3 + slot_cur, f);
            }
            float b0 = fminf(powp(nuv.x / (ev.x * s0)),  HUGEV);
            float b1 = fminf(powp(nuv.y / (ev.y * s1)),  HUGEV);
            float b2 = fminf(powp(nuv.z / (ev.z * s2e)), HUGEV);
            float b3 = fminf(powp(nuv.w / (ev.w * s3)),  HUGEV);
            // b(t-1) > BIG  <=>  s2*ev*RTHR < nu  (mul form, no div/pow)
            bool hotb = (s0 * ev.x * RTHR < nuv.x) || (s1 * ev.y * RTHR < nuv.y) ||
                        (s2e * ev.z * RTHR < nuv.z) || (s3 * ev.w * RTHR < nuv.w);
            if (__any((int)hotb) && lane == 0)
                atomicOr(hb + slot_cur * 8 + beta, 1u);   // cross signal only
            int flag = __syncthreads_or((int)hotb | carry);
            if (flag) {
                // absorb(t-1): u += eps log a, v += eps log b, K rebuilt, b = 1
                float vn0 = EPSV * logf(b0) + vv.x;
                float vn1 = EPSV * logf(b1) + vv.y;
                float vn2 = EPSV * logf(b2) + vv.z;
                float vn3 = EPSV * logf(b3) + vv.w;
                if (tid < 32) {
                    float un = EPSV * logf(a_s[tid]) + u_s[tid];
                    u_s[tid] = un;  eu_s[tid] = expf(un);
                }
                vv = make_float4(vn0, vn1, vn2, vn3);
                ev = make_float4(expf(vn0), expf(vn1), expf(vn2), expf(vn3));
                bu = make_float4(1.f, 1.f, 1.f, 1.f);
                __syncthreads();
                #pragma unroll
                for (int i = 0; i < 16; ++i) {
                    float4 cv = *reinterpret_cast<const float4*>(C + kbase + i * 1024);
                    float un = u_s[p * 16 + i];
                    kr[i].x = fminf(expf((un + vn0 - cv.x) * 10.0f), HUGEV);
                    kr[i].y = fminf(expf((un + vn1 - cv.y) * 10.0f), HUGEV);
                    kr[i].z = fminf(expf((un + vn2 - cv.z) * 10.0f), HUGEV);
                    kr[i].w = fminf(expf((un + vn3 - cv.w) * 10.0f), HUGEV);
                }
            } else {
                bu = make_float4(b0, b1, b2, b3);
            }
        }

        // ---- row pass: s_i = sum_j K_ij b_j dy ; a_i ------------------------
        float part[8];
        #pragma unroll
        for (int i = 0; i < 8; ++i)
            part[i] = kr[i].x * bu.x + kr[i].y * bu.y + kr[i].z * bu.z + kr[i].w * bu.w;
        fold_rows8(part, lane, red_s, w, 0);
        #pragma unroll
        for (int i = 0; i < 8; ++i)
            part[i] = kr[i + 8].x * bu.x + kr[i + 8].y * bu.y + kr[i + 8].z * bu.z + kr[i + 8].w * bu.w;
        fold_rows8(part, lane, red_s, w, 8);
        __syncthreads();
        if (tid < 32) {
            const float* rb = red_s + (tid >> 4) * 64 + (tid & 15);
            float s  = (rb[0] + rb[16] + rb[32] + rb[48]) * DYV;
            float rr = muv / (eu_s[tid] * s);
            float av = fminf(powp(rr), HUGEV);
            a_s[tid] = av;
            if (__any((int)(rr > RTHR)) && tid == 0)
                atomicOr(ha + slot_cur * 8 + beta, 1u);
        }
        __syncthreads();

        // ---- col pass: panel partials -> LDS combine -> 1 atomic per col ----
        float c0 = 0.f, c1 = 0.f, c2 = 0.f, c3 = 0.f;
        #pragma unroll
        for (int i = 0; i < 16; ++i) {
            float ai = a_s[p * 16 + i];
            c0 += kr[i].x * ai; c1 += kr[i].y * ai;
            c2 += kr[i].z * ai; c3 += kr[i].w * ai;
        }
        *reinterpret_cast<float4*>(&s2p_s[p][col0]) = make_float4(c0, c1, c2, c3);
        __syncthreads();
        if (tid < 256) {
            int cc = tid << 2;
            float4 q0 = *reinterpret_cast<const float4*>(&s2p_s[0][cc]);
            float4 q1 = *reinterpret_cast<const float4*>(&s2p_s[1][cc]);
            float* d = s2 + slot_cur * 8192 + beta * 1024 + cc;
            atomicAdd(d + 0, (q0.x + q1.x) * DXV);
            atomicAdd(d + 1, (q0.y + q1.y) * DXV);
            atomicAdd(d + 2, (q0.z + q1.z) * DXV);
            atomicAdd(d + 3, (q0.w + q1.w) * DXV);
        }
        // zero own batch's cols of slot_next (32 chunks x 32 = 1024; last read t-1)
        if (tid < 32)
            astore(s2 + slot_next * 8192 + beta * 1024 + chunk * 32 + tid, 0.0f);
        if (chunk == 0 && tid == 0) {
            astoreu(ha + slot_next * 8 + beta, 0u);
            astoreu(hb + slot_next * 8 + beta, 0u);
            astoreu(xflag + beta * 3 + slot_next, 0u);
        }
        batch_barrier(myctr, 32u * (unsigned)(t + 1), tid);
    }

    // ---- final forced absorb (ii=49) + K output + reductions ---------------
    {
        const float* sp = s2 + ((NITER - 1) % 3) * 8192 + beta * 1024 + col0;
        float s0 = aload(sp + 0), s1 = aload(sp + 1);
        float s2e = aload(sp + 2), s3 = aload(sp + 3);
        float b0 = fminf(powp(nuv.x / (ev.x * s0)),  HUGEV);
        float b1 = fminf(powp(nuv.y / (ev.y * s1)),  HUGEV);
        float b2 = fminf(powp(nuv.z / (ev.z * s2e)), HUGEV);
        float b3 = fminf(powp(nuv.w / (ev.w * s3)),  HUGEV);
        float vn0 = EPSV * logf(b0) + vv.x;
        float vn1 = EPSV * logf(b1) + vv.y;
        float vn2 = EPSV * logf(b2) + vv.z;
        float vn3 = EPSV * logf(b3) + vv.w;
        if (tid < 32) u_s[tid] = EPSV * logf(a_s[tid]) + u_s[tid];
        __syncthreads();

        float* Kout = out + 24;
        float tacc = 0.f, cc0 = 0.f, cc1 = 0.f, cc2 = 0.f, cc3 = 0.f;
        float part[8];
        #pragma unroll
        for (int i = 0; i < 8; ++i) {
            int off = kbase + i * 1024;
            float4 cv = *reinterpret_cast<const float4*>(C + off);
            float un = u_s[p * 16 + i];
            float4 kv;
            kv.x = fminf(expf((un + vn0 - cv.x) * 10.0f), HUGEV);
            kv.y = fminf(expf((un + vn1 - cv.y) * 10.0f), HUGEV);
            kv.z = fminf(expf((un + vn2 - cv.z) * 10.0f), HUGEV);
            kv.w = fminf(expf((un + vn3 - cv.w) * 10.0f), HUGEV);
            *reinterpret_cast<float4*>(Kout + off) = kv;
            part[i] = kv.x + kv.y + kv.z + kv.w;
            tacc += kv.x * cv.x + kv.y * cv.y + kv.z * cv.z + kv.w * cv.w;
            cc0 += kv.x; cc1 += kv.y; cc2 += kv.z; cc3 += kv.w;
        }
        fold_rows8(part, lane, red_s, w, 0);
        #pragma unroll
        for (int i = 8; i < 16; ++i) {
            int off = kbase + i * 1024;
            float4 cv = *reinterpret_cast<const float4*>(C + off);
            float un = u_s[p * 16 + i];
            float4 kv;
            kv.x = fminf(expf((un + vn0 - cv.x) * 10.0f), HUGEV);
            kv.y = fminf(expf((un + vn1 - cv.y) * 10.0f), HUGEV);
            kv.z = fminf(expf((un + vn2 - cv.z) * 10.0f), HUGEV);
            kv.w = fminf(expf((un + vn3 - cv.w) * 10.0f), HUGEV);
            *reinterpret_cast<float4*>(Kout + off) = kv;
            part[i - 8] = kv.x + kv.y + kv.z + kv.w;
            tacc += kv.x * cv.x + kv.y * cv.y + kv.z * cv.z + kv.w * cv.w;
            cc0 += kv.x; cc1 += kv.y; cc2 += kv.z; cc3 += kv.w;
        }
        fold_rows8(part, lane, red_s, w, 8);

        *reinterpret_cast<float4*>(&s2p_s[p][col0]) = make_float4(cc0, cc1, cc2, cc3);

        float r = tacc;
        #pragma unroll
        for (int m = 32; m >= 1; m >>= 1) r += __shfl_xor(r, m);
        if (lane == 0) tr_s[w] = r;
        __syncthreads();

        if (tid < 256) {                    // rnu: panel combine -> atomic
            int cc = tid << 2;
            float4 q0 = *reinterpret_cast<const float4*>(&s2p_s[0][cc]);
            float4 q1 = *reinterpret_cast<const float4*>(&s2p_s[1][cc]);
            float* rn = rnu + beta * 1024 + cc;
            atomicAdd(rn + 0, (q0.x + q1.x) * DXV);
            atomicAdd(rn + 1, (q0.y + q1.y) * DXV);
            atomicAdd(rn + 2, (q0.z + q1.z) * DXV);
            atomicAdd(rn + 3, (q0.w + q1.w) * DXV);
        }
        if (tid < 32) {                     // cons1 partial for this block's rows
            const float* rb = red_s + (tid >> 4) * 64 + (tid & 15);
            float rmu = (rb[0] + rb[16] + rb[32] + rb[48]) * DYV;
            float dv = rmu / (muv + SMALLV);
            float kl = muv * (dv * logf(dv + SMALLV) - dv + 1.f);
            #pragma unroll
            for (int m = 32; m >= 1; m >>= 1) kl += __shfl_xor(kl, m);
            if (tid == 0) atomicAdd(accC1 + beta, kl * DXV);
        }
        if (tid == 0) {
            float tt = 0.f;
            #pragma unroll
            for (int i = 0; i < 8; ++i) tt += tr_s[i];
            atomicAdd(accT + beta, tt);
        }
        batch_barrier(myctr, 32u * (unsigned)(NITER + 1), tid);

        if (chunk == 0) {
            // cons2 + scalar outputs for batch beta
            if (tid < 256) {
                const float* rn = rnu + beta * 1024 + (tid << 2);
                float q0 = aload(rn + 0), q1 = aload(rn + 1);
                float q2 = aload(rn + 2), q3 = aload(rn + 3);
                float acc = 0.f;
                { float dv = q0 / (nuv.x + SMALLV); acc += nuv.x * (dv * logf(dv + SMALLV) - dv + 1.f); }
                { float dv = q1 / (nuv.y + SMALLV); acc += nuv.y * (dv * logf(dv + SMALLV) - dv + 1.f); }
                { float dv = q2 / (nuv.z + SMALLV); acc += nuv.z * (dv * logf(dv + SMALLV) - dv + 1.f); }
                { float dv = q3 / (nuv.w + SMALLV); acc += nuv.w * (dv * logf(dv + SMALLV) - dv + 1.f); }
                #pragma unroll
                for (int m = 32; m >= 1; m >>= 1) acc += __shfl_xor(acc, m);
                if (lane == 0) tr_s[w] = acc;    // waves 0..3
            }
            __syncthreads();
            if (tid == 0) {
                out[16 + beta] = (tr_s[0] + tr_s[1] + tr_s[2] + tr_s[3]) * DYV;
                out[beta]      = __hip_atomic_load(accT + beta,  __ATOMIC_RELAXED,
                                                   __HIP_MEMORY_SCOPE_AGENT) * (DXV * DYV);
                out[8 + beta]  = __hip_atomic_load(accC1 + beta, __ATOMIC_RELAXED,
                                                   __HIP_MEMORY_SCOPE_AGENT);
            }
        }
    }
}

extern "C" void kernel_launch(void* const* d_in, const int* in_sizes, int n_in,
                              void* d_out, int out_size, void* d_ws, size_t ws_size,
                              hipStream_t stream) {
    const float* C  = (const float*)d_in[0];   // [8,1024,1024]
    const float* mu = (const float*)d_in[1];   // [1024]
    const float* nu = (const float*)d_in[2];   // [1024]
    float* out = (float*)d_out;                // transport[8] cons1[8] cons2[8] K[8M]

    // ws layout (floats); total ~130 KB
    float* w     = (float*)d_ws;
    float* s2    = w;                          // [3][8][1024] rotating col sums
    float* rnu   = w + 24576;                  // [8][1024]
    float* accT  = w + 32768;                  // [8]
    float* accC1 = w + 32776;                  // [8]
    unsigned* bctr = (unsigned*)(w + 32784);   // [8 x 16] padded barrier counters
    unsigned* flg  = (unsigned*)(w + 32912);   // [72] ha[3][8]+hb[3][8]+xflag[8][3]

    hipLaunchKernelGGL(initws, dim3(32), dim3(256), 0, stream,
                       s2, rnu, accT, accC1, bctr, flg);

    void* args[] = { (void*)&C, (void*)&mu, (void*)&nu, (void*)&out,
                     (void*)&s2, (void*)&rnu, (void*)&bctr, (void*)&flg,
                     (void*)&accT, (void*)&accC1 };
    hipError_t err = hipLaunchCooperativeKernel((const void*)sinkhorn_persist,
                                                dim3(256), dim3(512), args, 0, stream);
    if (err != hipSuccess) {
        // Fallback: plain launch. 256 blocks = 1/CU on an otherwise-idle device,
        // so all blocks are co-resident and the spin barriers remain safe.
        hipLaunchKernelGGL(sinkhorn_persist, dim3(256), dim3(512), 0, stream,
                           C, mu, nu, out, s2, rnu, bctr, flg, accT, accC1);
    }
}